// Round 3
// baseline (1221.721 us; speedup 1.0000x reference)
//
#include <hip/hip_runtime.h>
#include <hip/hip_bf16.h>

typedef __attribute__((ext_vector_type(8))) short short8;
typedef __attribute__((ext_vector_type(4))) float f32x4;
typedef __attribute__((ext_vector_type(4))) unsigned int uint4v;

#define BM 256
#define BN 256
#define BK 64

// async global->LDS, 16B per lane. LDS dest must be wave-uniform base + lane*16.
__device__ __forceinline__ void gl_lds16(const __hip_bfloat16* g, __hip_bfloat16* l) {
  __builtin_amdgcn_global_load_lds((const __attribute__((address_space(1))) void*)g,
                                   (__attribute__((address_space(3))) void*)l,
                                   16, 0, 0);
}

// Fused prep: dequant (blocks [0, nDeq)) + x fp32->bf16 chunk transpose
// (blocks [nDeq, nDeq + nCvt)). Both 256-thread, block-uniform branch.
// Dequant: qweight [K/8, N] int4 -> W' chunks: chunk (kc, n) = W^T[n][kc*8..+8).
// Cvtx: x fp32 [M,K] -> X' chunks: chunk (kc, m) at index kc*M + m.
__global__ void prep_kernel(const int* __restrict__ qweight,
                            const int* __restrict__ qzeros,
                            const float* __restrict__ scales,
                            __hip_bfloat16* __restrict__ wp,
                            const float* __restrict__ x,
                            __hip_bfloat16* __restrict__ xp,
                            int N, int K, int M, int nDeq) {
  __shared__ __hip_bfloat16 tile[64 * 64];  // cvtx only (8KB)
  const int id = blockIdx.x;
  if (id < nDeq) {
    // ---- dequant ----
    const int nb = N >> 8;  // N/256 blocks per row
    const int n = (id % nb) * 256 + threadIdx.x;
    const int kc = id / nb;           // qweight row = k/8
    const int g = kc >> 4;            // (kc*8)/128
    const float s = scales[(size_t)g * N + n];
    const int zq = qzeros[(size_t)g * (N >> 3) + (n >> 3)];
    const float c = s * (float)((zq >> ((n & 7) * 4)) & 15);
    const int q = qweight[(size_t)kc * N + n];
    __hip_bfloat16 v[8];
#pragma unroll
    for (int j = 0; j < 8; j++)
      v[j] = __float2bfloat16(fmaf(s, (float)((q >> (4 * j)) & 15), -c));
    ((uint4v*)wp)[(size_t)kc * N + n] = *(const uint4v*)v;
  } else {
    // ---- cvtx: 64m x 64k tile, LDS transpose so both sides coalesce ----
    const int id2 = id - nDeq;
    const int mb = M >> 6;
    const int m0 = (id2 % mb) * 64, k0 = (id2 / mb) * 64;
    const int t = threadIdx.x;
    const int mr = t >> 2, cq = t & 3;  // 4 threads/row, 16 fp32 each
    const float4* src = (const float4*)(x + (size_t)(m0 + mr) * K + k0 + cq * 16);
    const float4 a = src[0], b = src[1], c = src[2], d = src[3];
    __hip_bfloat16 v[16];
    v[0] = __float2bfloat16(a.x);  v[1] = __float2bfloat16(a.y);
    v[2] = __float2bfloat16(a.z);  v[3] = __float2bfloat16(a.w);
    v[4] = __float2bfloat16(b.x);  v[5] = __float2bfloat16(b.y);
    v[6] = __float2bfloat16(b.z);  v[7] = __float2bfloat16(b.w);
    v[8] = __float2bfloat16(c.x);  v[9] = __float2bfloat16(c.y);
    v[10] = __float2bfloat16(c.z); v[11] = __float2bfloat16(c.w);
    v[12] = __float2bfloat16(d.x); v[13] = __float2bfloat16(d.y);
    v[14] = __float2bfloat16(d.z); v[15] = __float2bfloat16(d.w);
    *(uint4v*)&tile[((cq * 2 + 0) * 64 + mr) * 8] = *(const uint4v*)&v[0];
    *(uint4v*)&tile[((cq * 2 + 1) * 64 + mr) * 8] = *(const uint4v*)&v[8];
    __syncthreads();
#pragma unroll
    for (int j = 0; j < 2; j++) {
      const int s = j * 256 + t;
      const int c8 = s >> 6, m = s & 63;
      ((uint4v*)xp)[(size_t)((k0 >> 3) + c8) * M + m0 + m] = *(const uint4v*)&tile[s * 8];
    }
  }
}

// 256x256 8-wave bf16 GEMM, m201-style quadrant phases: C = X W^T + bias.
// Per K-tile t, 4 phases = 4 C-quadrants of the per-wave 128x64 tile, each
// covering full K=64 (2 ks). Cross-phase fragment reuse in registers balances
// LDS reads per phase to 12/4/8/0 (vs 10/2/10/2 before), so each phase's
// lgkmcnt(0) gates on few (or zero) new reads and the LDS pipe drains under
// the previous phase's MFMA window.
//   ph0 (mh0,nh0): read A0(8)+B0(4); stage (t+1).h3 -> nxt
//   ph1 (mh0,nh1): read B1(4)       ; [no free cur region yet]
//   ph2 (mh1,nh1): read A1(8)       ; stage (t+2).h2 -> cur (h2/h3 free after ph1)
//   ph3 (mh1,nh0): read none (B0 held); stage (t+2).h0+h1 -> cur; vmcnt(6)
// Regions: h0=A chunks0-3, h1=A chunks4-7, h2=B chunks0-3, h3=B chunks4-7.
// Overwrite safety: a region staged in phase p was last READ in phase <= p-1;
// that phase's end barrier comes after every wave's lgkmcnt(0) -> reads landed.
// vmcnt ledger (instr/wave): prologue 14 -> vmcnt(6); steady: +2(ph0) +2(ph2)
// +4(ph3) = 14 -> vmcnt(6) retires all of tile t+1. Drain 0 at t==NT-2.
__global__ __launch_bounds__(512, 2) void gemm_kernel(
    const __hip_bfloat16* __restrict__ Xp,  // chunks [K/8][M]
    const __hip_bfloat16* __restrict__ Wp,  // chunks [K/8][N]
    const float* __restrict__ bias,
    float* __restrict__ C, int M, int N, int K) {
  __shared__ __hip_bfloat16 As[2][8 * 256 * 8];  // 32KB per buf
  __shared__ __hip_bfloat16 Bs[2][8 * 256 * 8];  // total 128KB
  const int tid = threadIdx.x;
  const int m0 = blockIdx.x * BM;  // x fastest => consecutive blocks share n0
  const int n0 = blockIdx.y * BN;
  const int wid = tid >> 6, ln = tid & 63;
  const int wmoff = (wid >> 2) * 128;  // 2 waves in M
  const int wnoff = (wid & 3) * 64;    // 4 waves in N
  const int lr = ln & 15, q4 = ln >> 4;

  f32x4 acc[8][4] = {};
  const int NT = K >> 6;  // K-tiles of 64

  auto stageA = [&](int t, int hs, int buf) {
#pragma unroll
    for (int i = 0; i < 2; ++i) {
      const int s = i * 512 + tid;
      const int c8 = (hs << 2) + (s >> 8);
      const int row = s & 255;
      gl_lds16(Xp + ((size_t)(t * 8 + c8) * M + m0 + row) * 8,
               &As[buf][(c8 * 256 + row) * 8]);
    }
  };
  auto stageB = [&](int t, int hs, int buf) {
#pragma unroll
    for (int i = 0; i < 2; ++i) {
      const int s = i * 512 + tid;
      const int c8 = (hs << 2) + (s >> 8);
      const int row = s & 255;
      gl_lds16(Wp + ((size_t)(t * 8 + c8) * N + n0 + row) * 8,
               &Bs[buf][(c8 * 256 + row) * 8]);
    }
  };

  // Prologue: tile0 all 4 halves, tile1 h0,h2,h1 (h3 comes in tile0.phase0).
  stageA(0, 0, 0); stageA(0, 1, 0); stageB(0, 0, 0); stageB(0, 1, 0);
  if (NT > 1) {
    stageA(1, 0, 1); stageB(1, 0, 1); stageA(1, 1, 1);
    asm volatile("s_waitcnt vmcnt(6)" ::: "memory");  // tile0's 8 loads retired
  } else {
    asm volatile("s_waitcnt vmcnt(0)" ::: "memory");
  }
  __builtin_amdgcn_s_barrier();

  short8 a[2][4], b0[2][2], b1[2][2];

  for (int t = 0; t < NT; ++t) {
    const int cur = t & 1, nxt = cur ^ 1;
    const __hip_bfloat16* Ac = As[cur];
    const __hip_bfloat16* Bc = Bs[cur];

    // -- phase 0: quadrant (mh0,nh0). Read A-half0 (8) + B-half0 (4).
#pragma unroll
    for (int ks = 0; ks < 2; ++ks) {
#pragma unroll
      for (int mf = 0; mf < 4; ++mf)
        a[ks][mf] = *(const short8*)&Ac[((ks * 4 + q4) * 256 + wmoff + mf * 16 + lr) * 8];
#pragma unroll
      for (int nf = 0; nf < 2; ++nf)
        b0[ks][nf] = *(const short8*)&Bc[((ks * 4 + q4) * 256 + wnoff + nf * 16 + lr) * 8];
    }
    if (t + 1 < NT) stageB(t + 1, 1, nxt);
    __builtin_amdgcn_s_barrier();
    asm volatile("s_waitcnt lgkmcnt(0)" ::: "memory");
    __builtin_amdgcn_s_setprio(1);
#pragma unroll
    for (int mf = 0; mf < 4; ++mf)
#pragma unroll
      for (int nf = 0; nf < 2; ++nf) {
        acc[mf][nf] = __builtin_amdgcn_mfma_f32_16x16x32_bf16(a[0][mf], b0[0][nf], acc[mf][nf], 0, 0, 0);
        acc[mf][nf] = __builtin_amdgcn_mfma_f32_16x16x32_bf16(a[1][mf], b0[1][nf], acc[mf][nf], 0, 0, 0);
      }
    __builtin_amdgcn_s_setprio(0);
    __builtin_amdgcn_s_barrier();

    // -- phase 1: quadrant (mh0,nh1). Read B-half1 (4); A-half0 reused.
#pragma unroll
    for (int ks = 0; ks < 2; ++ks)
#pragma unroll
      for (int nf = 0; nf < 2; ++nf)
        b1[ks][nf] = *(const short8*)&Bc[((ks * 4 + q4) * 256 + wnoff + 32 + nf * 16 + lr) * 8];
    __builtin_amdgcn_s_barrier();
    asm volatile("s_waitcnt lgkmcnt(0)" ::: "memory");
    __builtin_amdgcn_s_setprio(1);
#pragma unroll
    for (int mf = 0; mf < 4; ++mf)
#pragma unroll
      for (int nf = 0; nf < 2; ++nf) {
        acc[mf][2 + nf] = __builtin_amdgcn_mfma_f32_16x16x32_bf16(a[0][mf], b1[0][nf], acc[mf][2 + nf], 0, 0, 0);
        acc[mf][2 + nf] = __builtin_amdgcn_mfma_f32_16x16x32_bf16(a[1][mf], b1[1][nf], acc[mf][2 + nf], 0, 0, 0);
      }
    __builtin_amdgcn_s_setprio(0);
    __builtin_amdgcn_s_barrier();

    // -- phase 2: quadrant (mh1,nh1). Read A-half1 (8); B-half1 reused.
    //    Stage (t+2).h2 -> cur (B chunks0-3: last read ph1).
#pragma unroll
    for (int ks = 0; ks < 2; ++ks)
#pragma unroll
      for (int mf = 0; mf < 4; ++mf)
        a[ks][mf] = *(const short8*)&Ac[((ks * 4 + q4) * 256 + wmoff + 64 + mf * 16 + lr) * 8];
    if (t + 2 < NT) stageB(t + 2, 0, cur);
    __builtin_amdgcn_s_barrier();
    asm volatile("s_waitcnt lgkmcnt(0)" ::: "memory");
    __builtin_amdgcn_s_setprio(1);
#pragma unroll
    for (int mf = 0; mf < 4; ++mf)
#pragma unroll
      for (int nf = 0; nf < 2; ++nf) {
        acc[4 + mf][2 + nf] = __builtin_amdgcn_mfma_f32_16x16x32_bf16(a[0][mf], b1[0][nf], acc[4 + mf][2 + nf], 0, 0, 0);
        acc[4 + mf][2 + nf] = __builtin_amdgcn_mfma_f32_16x16x32_bf16(a[1][mf], b1[1][nf], acc[4 + mf][2 + nf], 0, 0, 0);
      }
    __builtin_amdgcn_s_setprio(0);
    __builtin_amdgcn_s_barrier();

    // -- phase 3: quadrant (mh1,nh0). No reads (B-half0 held since ph0).
    //    Stage (t+2).h0+h1 -> cur (A chunks: last read ph2); counted vmcnt.
    if (t + 2 < NT) { stageA(t + 2, 0, cur); stageA(t + 2, 1, cur); }
    if (t == NT - 2) asm volatile("s_waitcnt vmcnt(0)" ::: "memory");
    else             asm volatile("s_waitcnt vmcnt(6)" ::: "memory");
    __builtin_amdgcn_s_barrier();
    __builtin_amdgcn_s_setprio(1);
#pragma unroll
    for (int mf = 0; mf < 4; ++mf)
#pragma unroll
      for (int nf = 0; nf < 2; ++nf) {
        acc[4 + mf][nf] = __builtin_amdgcn_mfma_f32_16x16x32_bf16(a[0][mf], b0[0][nf], acc[4 + mf][nf], 0, 0, 0);
        acc[4 + mf][nf] = __builtin_amdgcn_mfma_f32_16x16x32_bf16(a[1][mf], b0[1][nf], acc[4 + mf][nf], 0, 0, 0);
      }
    __builtin_amdgcn_s_setprio(0);
    __builtin_amdgcn_s_barrier();
  }

  // C/D layout: col = lane&15, row = (lane>>4)*4 + reg  [m89/m91-verified]
  const int cr = m0 + wmoff + q4 * 4;
  const int cc = n0 + wnoff + lr;
#pragma unroll
  for (int nf = 0; nf < 4; ++nf) {
    const float bv = bias[cc + nf * 16];
#pragma unroll
    for (int mf = 0; mf < 8; ++mf) {
#pragma unroll
      for (int r = 0; r < 4; ++r) {
        C[(size_t)(cr + mf * 16 + r) * N + cc + nf * 16] = acc[mf][nf][r] + bv;
      }
    }
  }
}

// Correct-but-slow fallback if workspace/shapes don't conform (diagnostic path).
__global__ void naive_kernel(const float* __restrict__ x, const int* __restrict__ qweight,
                             const int* __restrict__ qzeros, const float* __restrict__ scales,
                             const float* __restrict__ bias, const int* __restrict__ g_idx,
                             float* __restrict__ out, int in_f, int out_f) {
  const int n = blockIdx.x * blockDim.x + threadIdx.x;
  if (n >= out_f) return;
  const int m = blockIdx.y;
  const float* xr = x + (size_t)m * in_f;
  float acc = 0.f;
  for (int kk = 0; kk < (in_f >> 3); kk++) {
    const int q = qweight[(size_t)kk * out_f + n];
    const int g = g_idx[kk * 8];
    const float s = scales[(size_t)g * out_f + n];
    const int z = (qzeros[(size_t)g * (out_f >> 3) + (n >> 3)] >> ((n & 7) * 4)) & 15;
    float part = 0.f;
#pragma unroll
    for (int j = 0; j < 8; j++)
      part += xr[kk * 8 + j] * (float)(((q >> (4 * j)) & 15) - z);
    acc += s * part;
  }
  out[(size_t)m * out_f + n] = acc + bias[n];
}

extern "C" void kernel_launch(void* const* d_in, const int* in_sizes, int n_in,
                              void* d_out, int out_size, void* d_ws, size_t ws_size,
                              hipStream_t stream) {
  const float* x = (const float*)d_in[0];
  const int* qweight = (const int*)d_in[1];
  const int* qzeros = (const int*)d_in[2];
  const float* scales = (const float*)d_in[3];
  const float* bias = (const float*)d_in[4];
  const int* g_idx = (const int*)d_in[5];
  float* out = (float*)d_out;

  const int out_f = in_sizes[4];          // bias length (N)
  const int in_f = in_sizes[5];           // g_idx length (K)
  const int tokens = in_sizes[0] / in_f;  // x rows (M)

  const size_t need_w = (size_t)in_f * out_f * sizeof(__hip_bfloat16);
  const size_t need_x = (size_t)tokens * in_f * sizeof(__hip_bfloat16);

  if (ws_size >= need_w + need_x && (in_f % 128) == 0 && (out_f % 256) == 0 &&
      (tokens % 256) == 0) {
    __hip_bfloat16* wp = (__hip_bfloat16*)d_ws;
    __hip_bfloat16* xp = (__hip_bfloat16*)((char*)d_ws + need_w);
    const int nDeq = (out_f >> 8) * (in_f >> 3);
    const int nCvt = (tokens >> 6) * (in_f >> 6);
    prep_kernel<<<dim3(nDeq + nCvt), 256, 0, stream>>>(
        qweight, qzeros, scales, wp, x, xp, out_f, in_f, tokens, nDeq);
    gemm_kernel<<<dim3(tokens / BM, out_f / BN), 512, 0, stream>>>(
        xp, wp, bias, out, tokens, out_f, in_f);
  } else {
    naive_kernel<<<dim3((out_f + 255) / 256, tokens), 256, 0, stream>>>(
        x, qweight, qzeros, scales, bias, g_idx, out, in_f, out_f);
  }
}